// Round 9
// baseline (296.136 us; speedup 1.0000x reference)
//
#include <hip/hip_runtime.h>
#include <hip/hip_bf16.h>
#include <math.h>

constexpr int B_   = 8;
constexpr int N_   = 2048;
constexpr int FIN  = 256;
constexpr int FOUT = 128;

constexpr int CH  = 512;          // K-chunk length
constexpr int NCH = N_ / CH;      // 4 chunks
constexpr int PR  = CH + 8;       // 520 shorts per LDS P row (pad)
constexpr int XR  = FIN + 8;      // 264 shorts per xs row (ka pad)
constexpr int TR  = 40;           // ka transpose-tile row stride

typedef __attribute__((ext_vector_type(8))) short bf16x8;
typedef __attribute__((ext_vector_type(4))) float f32x4;
typedef __attribute__((ext_vector_type(4))) int   i32x4;

static __device__ __forceinline__ unsigned short f2bf(float f) {
    __hip_bfloat16 h = __float2bfloat16(f);
    return *reinterpret_cast<unsigned short*>(&h);
}
static __device__ __forceinline__ i32x4 ntload4(const int* p) {
    return __builtin_nontemporal_load((const i32x4*)p);
}

// ---------------------------------------------------------------------------
// K0: Wt[n][k] = bf16(W[k][n])  (dim-major weight, 64 KB). Tiny.
// ---------------------------------------------------------------------------
__global__ __launch_bounds__(256) void k0_wt(const float* __restrict__ W,
                                             unsigned short* __restrict__ Wt) {
    const int n = blockIdx.x;   // 0..127
    const int k = threadIdx.x;  // 0..255
    Wt[n * FIN + k] = f2bf(W[k * FOUT + n]);
}

// ---------------------------------------------------------------------------
// KA: WhT[b][d][j] = (x@W)^T via MFMA + fused f1/f2 = Wh.a1 / Wh.a2.
// (unchanged — proven since R6, ~13 us)
// ---------------------------------------------------------------------------
__global__ __launch_bounds__(256) void ka_wh(const float* __restrict__ x,
                                             const unsigned short* __restrict__ Wt,
                                             const float* __restrict__ a,
                                             unsigned short* __restrict__ WhT,
                                             float* __restrict__ f1,
                                             float* __restrict__ f2) {
    __shared__ unsigned short xs[32 * XR];   // 16.5 KB; reused as T[128][TR]
    __shared__ float as[2 * FOUT];           // 1 KB
    __shared__ float fred[2][4][32];         // 1 KB

    const int tid = threadIdx.x;
    const int j0  = blockIdx.x * 32;
    const int b   = j0 >> 11;
    const int jb  = j0 & (N_ - 1);

    if (tid < 2 * FOUT) as[tid] = a[tid];
    {
        const float4* xsrc = (const float4*)(x + (size_t)j0 * FIN);
#pragma unroll
        for (int t = 0; t < 8; ++t) {
            const int idx = tid + t * 256;
            float4 v = xsrc[idx];
            const int row = idx >> 6, c4 = idx & 63;
            ushort4 u;
            u.x = f2bf(v.x); u.y = f2bf(v.y); u.z = f2bf(v.z); u.w = f2bf(v.w);
            *(ushort4*)&xs[row * XR + c4 * 4] = u;
        }
    }
    __syncthreads();

    const int wave = tid >> 6, lane = tid & 63;
    const int quad = lane >> 4, l16 = lane & 15;

    f32x4 acc[2][2];
#pragma unroll
    for (int aa = 0; aa < 2; ++aa)
#pragma unroll
        for (int nn = 0; nn < 2; ++nn) acc[aa][nn] = {0.f, 0.f, 0.f, 0.f};

    const unsigned short* wtA0 = Wt + (size_t)(32 * wave + l16) * FIN;
    const unsigned short* wtA1 = wtA0 + 16 * FIN;
#pragma unroll
    for (int ks = 0; ks < FIN / 32; ++ks) {
        const int kof = ks * 32 + quad * 8;
        bf16x8 af0 = *(const bf16x8*)&wtA0[kof];
        bf16x8 af1 = *(const bf16x8*)&wtA1[kof];
        bf16x8 bf0 = *(const bf16x8*)&xs[l16 * XR + kof];
        bf16x8 bf1 = *(const bf16x8*)&xs[(16 + l16) * XR + kof];
        acc[0][0] = __builtin_amdgcn_mfma_f32_16x16x32_bf16(af0, bf0, acc[0][0], 0, 0, 0);
        acc[0][1] = __builtin_amdgcn_mfma_f32_16x16x32_bf16(af0, bf1, acc[0][1], 0, 0, 0);
        acc[1][0] = __builtin_amdgcn_mfma_f32_16x16x32_bf16(af1, bf0, acc[1][0], 0, 0, 0);
        acc[1][1] = __builtin_amdgcn_mfma_f32_16x16x32_bf16(af1, bf1, acc[1][1], 0, 0, 0);
    }
    __syncthreads();

    unsigned short* T = xs;   // [128][TR]
    float pf[2][2] = {{0.f, 0.f}, {0.f, 0.f}};
#pragma unroll
    for (int aa = 0; aa < 2; ++aa)
#pragma unroll
        for (int nn = 0; nn < 2; ++nn)
#pragma unroll
            for (int r = 0; r < 4; ++r) {
                const int d = 32 * wave + 16 * aa + 4 * quad + r;
                const float v = acc[aa][nn][r];
                T[d * TR + nn * 16 + l16] = f2bf(v);
                pf[0][nn] += v * as[d];
                pf[1][nn] += v * as[FOUT + d];
            }
#pragma unroll
    for (int ff = 0; ff < 2; ++ff)
#pragma unroll
        for (int nn = 0; nn < 2; ++nn) {
            float v = pf[ff][nn];
            v += __shfl_xor(v, 16);
            v += __shfl_xor(v, 32);
            pf[ff][nn] = v;
        }
    if (quad == 0) {
#pragma unroll
        for (int ff = 0; ff < 2; ++ff)
#pragma unroll
            for (int nn = 0; nn < 2; ++nn)
                fred[ff][wave][nn * 16 + l16] = pf[ff][nn];
    }
    __syncthreads();

    unsigned short* dstW = WhT + (size_t)b * FOUT * N_;
#pragma unroll
    for (int it = 0; it < 2; ++it) {
        const int idx = it * 256 + tid;
        const int d = idx >> 2, q = idx & 3;
        bf16x8 v = *(const bf16x8*)&T[d * TR + q * 8];
        *(bf16x8*)&dstW[(size_t)d * N_ + jb + q * 8] = v;
    }
    if (tid < 64) {
        const int ff = tid >> 5, j32 = tid & 31;
        const float s = fred[ff][0][j32] + fred[ff][1][j32] +
                        fred[ff][2][j32] + fred[ff][3][j32];
        (ff ? f2 : f1)[(size_t)b * N_ + jb + j32] = s;
    }
}

// ---------------------------------------------------------------------------
// KP: R6's Phase A, decoupled. Computes P = exp(leaky(f1+f2)) masked by adj
// (unnormalized, bf16) to GLOBAL, plus per-row sums. Wave w owns rows
// i0+4w..i0+4w+3 entirely (all 4 chunks) — ZERO barriers, zero LDS, pure
// HBM stream. adj via nontemporal loads. 1024 blocks x 256.
// ---------------------------------------------------------------------------
__global__ __launch_bounds__(256) void kp_p(const int* __restrict__ adj,
                                            const float* __restrict__ f1,
                                            const float* __restrict__ f2,
                                            unsigned short* __restrict__ P,
                                            float* __restrict__ rsum) {
    const int tid  = threadIdx.x;
    const int b    = blockIdx.x & 7;
    const int i0   = (blockIdx.x >> 3) * 16;
    const int wave = tid >> 6, lane = tid & 63;

    const float4* f2b4 = (const float4*)(f2 + (size_t)b * N_);
    unsigned short* Pb = P + ((size_t)b * N_ + i0) * N_;

    float f1r[4], s_run[4];
#pragma unroll
    for (int rr = 0; rr < 4; ++rr) {
        f1r[rr]   = f1[(size_t)b * N_ + i0 + wave * 4 + rr];
        s_run[rr] = 0.f;
    }

    for (int c = 0; c < NCH; ++c) {
        const float4 fv0 = f2b4[c * (CH / 4) + lane];
        const float4 fv1 = f2b4[c * (CH / 4) + 64 + lane];
#pragma unroll
        for (int rr = 0; rr < 4; ++rr) {
            const int ti = wave * 4 + rr;
            const int* arow = adj + ((size_t)b * N_ + i0 + ti) * N_ + c * CH;
            const i32x4 av0 = ntload4(arow + 4 * lane);
            const i32x4 av1 = ntload4(arow + 256 + 4 * lane);
            const float f1i = f1r[rr];

            float e[8];
            e[0] = f1i + fv0.x; e[1] = f1i + fv0.y; e[2] = f1i + fv0.z; e[3] = f1i + fv0.w;
            e[4] = f1i + fv1.x; e[5] = f1i + fv1.y; e[6] = f1i + fv1.z; e[7] = f1i + fv1.w;
#pragma unroll
            for (int q = 0; q < 8; ++q) e[q] = (e[q] >= 0.f) ? e[q] : 2.f * e[q];

            float pv[8];
            pv[0] = (av0.x > 0) ? __expf(e[0]) : 0.f;
            pv[1] = (av0.y > 0) ? __expf(e[1]) : 0.f;
            pv[2] = (av0.z > 0) ? __expf(e[2]) : 0.f;
            pv[3] = (av0.w > 0) ? __expf(e[3]) : 0.f;
            pv[4] = (av1.x > 0) ? __expf(e[4]) : 0.f;
            pv[5] = (av1.y > 0) ? __expf(e[5]) : 0.f;
            pv[6] = (av1.z > 0) ? __expf(e[6]) : 0.f;
            pv[7] = (av1.w > 0) ? __expf(e[7]) : 0.f;
            s_run[rr] += ((pv[0] + pv[1]) + (pv[2] + pv[3])) +
                         ((pv[4] + pv[5]) + (pv[6] + pv[7]));

            ushort4 u0, u1;
            u0.x = f2bf(pv[0]); u0.y = f2bf(pv[1]); u0.z = f2bf(pv[2]); u0.w = f2bf(pv[3]);
            u1.x = f2bf(pv[4]); u1.y = f2bf(pv[5]); u1.z = f2bf(pv[6]); u1.w = f2bf(pv[7]);
            *(ushort4*)&Pb[(size_t)ti * N_ + c * CH + 4 * lane]       = u0;
            *(ushort4*)&Pb[(size_t)ti * N_ + c * CH + 256 + 4 * lane] = u1;
        }
    }

#pragma unroll
    for (int rr = 0; rr < 4; ++rr) {
        float s = s_run[rr];
#pragma unroll
        for (int o = 32; o; o >>= 1) s += __shfl_xor(s, o);
        if (lane == 0) rsum[(size_t)b * N_ + i0 + wave * 4 + rr] = s;
    }
}

// ---------------------------------------------------------------------------
// KB: pure GEMM O = P @ Wh, /rowsum, ELU. R6's Phase B byte-for-byte; Phase A
// replaced by plain coalesced global->LDS staging of the P chunk (no exp
// chain -> loads pipeline deeply). Double-buffered (33 KB LDS, 4 blocks/CU),
// ONE barrier per chunk. 16 rows/block, 1024 blocks; b=blockIdx&7 keeps the
// batch's 512 KB WhT slab XCD-pinned in L2.
// ---------------------------------------------------------------------------
__global__ __launch_bounds__(256) void kb_gemm(const unsigned short* __restrict__ P,
                                               const unsigned short* __restrict__ WhT,
                                               const float* __restrict__ rsum,
                                               float* __restrict__ out) {
    __shared__ unsigned short p[2][16 * PR];  // 33.3 KB

    const int tid  = threadIdx.x;
    const int b    = blockIdx.x & 7;
    const int i0   = (blockIdx.x >> 3) * 16;
    const int wave = tid >> 6, lane = tid & 63;
    const int quad = lane >> 4, l16 = lane & 15;

    const unsigned short* Pb = P + ((size_t)b * N_ + i0) * N_;
    const int srow = tid >> 4;          // staging: row 0..15
    const int scol = (tid & 15) * 32;   // staging: 32-short (64B) slice

    const int n0 = wave * 32;
    const unsigned short* wB0 = WhT + (size_t)b * FOUT * N_ + (size_t)(n0 + l16) * N_;
    const unsigned short* wB1 = wB0 + (size_t)16 * N_;

    f32x4 acc0 = {0.f, 0.f, 0.f, 0.f}, acc1 = {0.f, 0.f, 0.f, 0.f};

    // stage chunk 0
#pragma unroll
    for (int q = 0; q < 4; ++q) {
        const bf16x8 v = *(const bf16x8*)&Pb[(size_t)srow * N_ + scol + q * 8];
        *(bf16x8*)&p[0][srow * PR + scol + q * 8] = v;
    }
    __syncthreads();

    for (int c = 0; c < NCH; ++c) {
        if (c + 1 < NCH) {   // stage next chunk into the other buffer
#pragma unroll
            for (int q = 0; q < 4; ++q) {
                const bf16x8 v =
                    *(const bf16x8*)&Pb[(size_t)srow * N_ + (c + 1) * CH + scol + q * 8];
                *(bf16x8*)&p[(c + 1) & 1][srow * PR + scol + q * 8] = v;
            }
        }

        const unsigned short* pA = &p[c & 1][l16 * PR];
        const int kbase = c * CH;
#pragma unroll
        for (int ks = 0; ks < CH / 32; ++ks) {
            const int kof = ks * 32 + quad * 8;
            bf16x8 afr = *(const bf16x8*)&pA[kof];
            bf16x8 b0  = *(const bf16x8*)&wB0[kbase + kof];
            bf16x8 b1  = *(const bf16x8*)&wB1[kbase + kof];
            acc0 = __builtin_amdgcn_mfma_f32_16x16x32_bf16(afr, b0, acc0, 0, 0, 0);
            acc1 = __builtin_amdgcn_mfma_f32_16x16x32_bf16(afr, b1, acc1, 0, 0, 0);
        }
        __syncthreads();
    }

    // ---- Epilogue: /rowsum, ELU, store (row m = quad*4+r, col n = l16) ----
#pragma unroll
    for (int r = 0; r < 4; ++r) {
        const int m = quad * 4 + r;
        const float inv = 1.f / rsum[(size_t)b * N_ + i0 + m];
        float v0 = acc0[r] * inv;
        float v1 = acc1[r] * inv;
        v0 = (v0 > 0.f) ? v0 : expm1f(v0);
        v1 = (v1 > 0.f) ? v1 : expm1f(v1);
        const size_t base = ((size_t)b * N_ + i0 + m) * FOUT + n0;
        out[base + l16]      = v0;
        out[base + 16 + l16] = v1;
    }
}

// ---------------------------------------------------------------------------
extern "C" void kernel_launch(void* const* d_in, const int* in_sizes, int n_in,
                              void* d_out, int out_size, void* d_ws, size_t ws_size,
                              hipStream_t stream) {
    const float* x   = (const float*)d_in[0];
    const int*   adj = (const int*)d_in[1];
    const float* W   = (const float*)d_in[2];
    const float* a   = (const float*)d_in[3];
    float* out = (float*)d_out;

    // ws: WhT bf16 (4 MB) | Wt bf16 (64 KB) | f1 | f2 | rsum (64 KB each)
    //     | P bf16 (64 MB)   — total ~72 MB
    unsigned short* WhT = (unsigned short*)d_ws;
    unsigned short* Wt  = WhT + (size_t)B_ * FOUT * N_;
    float* f1   = (float*)(Wt + (size_t)FOUT * FIN);
    float* f2   = f1 + (size_t)B_ * N_;
    float* rsum = f2 + (size_t)B_ * N_;
    unsigned short* P = (unsigned short*)(rsum + (size_t)B_ * N_);

    hipLaunchKernelGGL(k0_wt, dim3(FOUT), dim3(FIN), 0, stream, W, Wt);
    hipLaunchKernelGGL(ka_wh, dim3(B_ * N_ / 32), dim3(256), 0, stream,
                       x, Wt, a, WhT, f1, f2);
    hipLaunchKernelGGL(kp_p, dim3(B_ * N_ / 16), dim3(256), 0, stream,
                       adj, f1, f2, P, rsum);
    hipLaunchKernelGGL(kb_gemm, dim3(B_ * N_ / 16), dim3(256), 0, stream,
                       P, WhT, rsum, out);
}

// Round 10
// 268.158 us; speedup vs baseline: 1.1043x; 1.1043x over previous
//
#include <hip/hip_runtime.h>
#include <hip/hip_bf16.h>
#include <math.h>

constexpr int B_   = 8;
constexpr int N_   = 2048;
constexpr int FIN  = 256;
constexpr int FOUT = 128;

constexpr int CH  = 512;          // K-chunk length
constexpr int NCH = N_ / CH;      // 4 chunks
constexpr int PR  = CH + 8;       // 520 shorts per LDS P row (pad)
constexpr int XR  = FIN + 8;      // 264 shorts per xs row (ka pad)
constexpr int TR  = 40;           // ka transpose-tile row stride

typedef __attribute__((ext_vector_type(8))) short bf16x8;
typedef __attribute__((ext_vector_type(4))) float f32x4;
typedef __attribute__((ext_vector_type(4))) int   i32x4;

static __device__ __forceinline__ unsigned short f2bf(float f) {
    __hip_bfloat16 h = __float2bfloat16(f);
    return *reinterpret_cast<unsigned short*>(&h);
}
static __device__ __forceinline__ i32x4 ntload4(const int* p) {
    return __builtin_nontemporal_load((const i32x4*)p);
}

// ---------------------------------------------------------------------------
// K0: Wt[n][k] = bf16(W[k][n])  (dim-major weight, 64 KB). Tiny.
// ---------------------------------------------------------------------------
__global__ __launch_bounds__(256) void k0_wt(const float* __restrict__ W,
                                             unsigned short* __restrict__ Wt) {
    const int n = blockIdx.x;   // 0..127
    const int k = threadIdx.x;  // 0..255
    Wt[n * FIN + k] = f2bf(W[k * FOUT + n]);
}

// ---------------------------------------------------------------------------
// KA: WhT[b][d][j] = (x@W)^T via MFMA + fused f1/f2 = Wh.a1 / Wh.a2.
// (unchanged — proven since R6)
// ---------------------------------------------------------------------------
__global__ __launch_bounds__(256) void ka_wh(const float* __restrict__ x,
                                             const unsigned short* __restrict__ Wt,
                                             const float* __restrict__ a,
                                             unsigned short* __restrict__ WhT,
                                             float* __restrict__ f1,
                                             float* __restrict__ f2) {
    __shared__ unsigned short xs[32 * XR];   // 16.5 KB; reused as T[128][TR]
    __shared__ float as[2 * FOUT];           // 1 KB
    __shared__ float fred[2][4][32];         // 1 KB

    const int tid = threadIdx.x;
    const int j0  = blockIdx.x * 32;
    const int b   = j0 >> 11;
    const int jb  = j0 & (N_ - 1);

    if (tid < 2 * FOUT) as[tid] = a[tid];
    {
        const float4* xsrc = (const float4*)(x + (size_t)j0 * FIN);
#pragma unroll
        for (int t = 0; t < 8; ++t) {
            const int idx = tid + t * 256;
            float4 v = xsrc[idx];
            const int row = idx >> 6, c4 = idx & 63;
            ushort4 u;
            u.x = f2bf(v.x); u.y = f2bf(v.y); u.z = f2bf(v.z); u.w = f2bf(v.w);
            *(ushort4*)&xs[row * XR + c4 * 4] = u;
        }
    }
    __syncthreads();

    const int wave = tid >> 6, lane = tid & 63;
    const int quad = lane >> 4, l16 = lane & 15;

    f32x4 acc[2][2];
#pragma unroll
    for (int aa = 0; aa < 2; ++aa)
#pragma unroll
        for (int nn = 0; nn < 2; ++nn) acc[aa][nn] = {0.f, 0.f, 0.f, 0.f};

    const unsigned short* wtA0 = Wt + (size_t)(32 * wave + l16) * FIN;
    const unsigned short* wtA1 = wtA0 + 16 * FIN;
#pragma unroll
    for (int ks = 0; ks < FIN / 32; ++ks) {
        const int kof = ks * 32 + quad * 8;
        bf16x8 af0 = *(const bf16x8*)&wtA0[kof];
        bf16x8 af1 = *(const bf16x8*)&wtA1[kof];
        bf16x8 bf0 = *(const bf16x8*)&xs[l16 * XR + kof];
        bf16x8 bf1 = *(const bf16x8*)&xs[(16 + l16) * XR + kof];
        acc[0][0] = __builtin_amdgcn_mfma_f32_16x16x32_bf16(af0, bf0, acc[0][0], 0, 0, 0);
        acc[0][1] = __builtin_amdgcn_mfma_f32_16x16x32_bf16(af0, bf1, acc[0][1], 0, 0, 0);
        acc[1][0] = __builtin_amdgcn_mfma_f32_16x16x32_bf16(af1, bf0, acc[1][0], 0, 0, 0);
        acc[1][1] = __builtin_amdgcn_mfma_f32_16x16x32_bf16(af1, bf1, acc[1][1], 0, 0, 0);
    }
    __syncthreads();

    unsigned short* T = xs;   // [128][TR]
    float pf[2][2] = {{0.f, 0.f}, {0.f, 0.f}};
#pragma unroll
    for (int aa = 0; aa < 2; ++aa)
#pragma unroll
        for (int nn = 0; nn < 2; ++nn)
#pragma unroll
            for (int r = 0; r < 4; ++r) {
                const int d = 32 * wave + 16 * aa + 4 * quad + r;
                const float v = acc[aa][nn][r];
                T[d * TR + nn * 16 + l16] = f2bf(v);
                pf[0][nn] += v * as[d];
                pf[1][nn] += v * as[FOUT + d];
            }
#pragma unroll
    for (int ff = 0; ff < 2; ++ff)
#pragma unroll
        for (int nn = 0; nn < 2; ++nn) {
            float v = pf[ff][nn];
            v += __shfl_xor(v, 16);
            v += __shfl_xor(v, 32);
            pf[ff][nn] = v;
        }
    if (quad == 0) {
#pragma unroll
        for (int ff = 0; ff < 2; ++ff)
#pragma unroll
            for (int nn = 0; nn < 2; ++nn)
                fred[ff][wave][nn * 16 + l16] = pf[ff][nn];
    }
    __syncthreads();

    unsigned short* dstW = WhT + (size_t)b * FOUT * N_;
#pragma unroll
    for (int it = 0; it < 2; ++it) {
        const int idx = it * 256 + tid;
        const int d = idx >> 2, q = idx & 3;
        bf16x8 v = *(const bf16x8*)&T[d * TR + q * 8];
        *(bf16x8*)&dstW[(size_t)d * N_ + jb + q * 8] = v;
    }
    if (tid < 64) {
        const int ff = tid >> 5, j32 = tid & 31;
        const float s = fred[ff][0][j32] + fred[ff][1][j32] +
                        fred[ff][2][j32] + fred[ff][3][j32];
        (ff ? f2 : f1)[(size_t)b * N_ + jb + j32] = s;
    }
}

// ---------------------------------------------------------------------------
// KB Phase A (R6-proven, verbatim): scores -> exp -> bf16 P chunk in LDS.
// All 64 lanes of a producer wave work row pw*4+rr, covering 512 columns.
// ---------------------------------------------------------------------------
static __device__ __forceinline__ void kb_phaseA(
    const int c, const int lane, const int pw, const int i0,
    const int* __restrict__ adjB, const float4* __restrict__ f2b4,
    const float* __restrict__ f1r, float* __restrict__ s_run,
    unsigned short* __restrict__ pb)
{
    const float4 fv0 = f2b4[c * (CH / 4) + lane];
    const float4 fv1 = f2b4[c * (CH / 4) + 64 + lane];
#pragma unroll
    for (int rr = 0; rr < 4; ++rr) {
        const int ti = pw * 4 + rr;
        const int i  = i0 + ti;
        const int* arow = adjB + (size_t)i * N_ + c * CH;
        const i32x4 av0 = ntload4(arow + 4 * lane);
        const i32x4 av1 = ntload4(arow + 256 + 4 * lane);
        const float f1i = f1r[rr];

        float e[8];
        e[0] = f1i + fv0.x; e[1] = f1i + fv0.y; e[2] = f1i + fv0.z; e[3] = f1i + fv0.w;
        e[4] = f1i + fv1.x; e[5] = f1i + fv1.y; e[6] = f1i + fv1.z; e[7] = f1i + fv1.w;
#pragma unroll
        for (int q = 0; q < 8; ++q) e[q] = (e[q] >= 0.f) ? e[q] : 2.f * e[q];

        float pv[8];
        pv[0] = (av0.x > 0) ? __expf(e[0]) : 0.f;
        pv[1] = (av0.y > 0) ? __expf(e[1]) : 0.f;
        pv[2] = (av0.z > 0) ? __expf(e[2]) : 0.f;
        pv[3] = (av0.w > 0) ? __expf(e[3]) : 0.f;
        pv[4] = (av1.x > 0) ? __expf(e[4]) : 0.f;
        pv[5] = (av1.y > 0) ? __expf(e[5]) : 0.f;
        pv[6] = (av1.z > 0) ? __expf(e[6]) : 0.f;
        pv[7] = (av1.w > 0) ? __expf(e[7]) : 0.f;
        s_run[rr] += ((pv[0] + pv[1]) + (pv[2] + pv[3])) +
                     ((pv[4] + pv[5]) + (pv[6] + pv[7]));

        ushort4 u0, u1;
        u0.x = f2bf(pv[0]); u0.y = f2bf(pv[1]); u0.z = f2bf(pv[2]); u0.w = f2bf(pv[3]);
        u1.x = f2bf(pv[4]); u1.y = f2bf(pv[5]); u1.z = f2bf(pv[6]); u1.w = f2bf(pv[7]);
        *(ushort4*)&pb[ti * PR + 4 * lane]       = u0;
        *(ushort4*)&pb[ti * PR + 256 + 4 * lane] = u1;
    }
}

// ---------------------------------------------------------------------------
// KB: wave-specialized fused masked softmax + P@WhT + ELU.
// 512 threads = 8 waves: waves 0-3 PRODUCE (R6 Phase A), waves 4-7 CONSUME
// (R6 Phase B, dims (wave-4)*32..). Unified step loop, ONE non-divergent
// barrier per step: A(step) and B(step-1) run CONCURRENTLY on different
// waves -> per-chunk critical path = max(A,B) instead of A+B (m114 overlap).
// LDS 33 KB -> 4 blocks/CU x 8 waves = 32 waves/CU (100%).
// ---------------------------------------------------------------------------
__global__ __launch_bounds__(512, 8) void kb_attn(const int* __restrict__ adj,
                                                  const unsigned short* __restrict__ WhT,
                                                  const float* __restrict__ f1,
                                                  const float* __restrict__ f2,
                                                  float* __restrict__ out) {
    __shared__ unsigned short p[2][16 * PR];  // 33.3 KB
    __shared__ float rs[16];

    const int tid  = threadIdx.x;
    const int b    = blockIdx.x & 7;          // XCD-pinned batch
    const int i0   = (blockIdx.x >> 3) * 16;
    const int wave = tid >> 6, lane = tid & 63;
    const int quad = lane >> 4, l16 = lane & 15;
    const bool producer = (wave < 4);
    const int  pw = wave & 3;                 // producer row-group / consumer dim-group

    const float4* f2b4 = (const float4*)(f2 + (size_t)b * N_);
    const int*    adjB = adj + (size_t)b * N_ * N_;

    float f1r[4], s_run[4];
#pragma unroll
    for (int rr = 0; rr < 4; ++rr) {
        f1r[rr]   = f1[(size_t)b * N_ + i0 + pw * 4 + rr];  // pw<=3 -> in bounds
        s_run[rr] = 0.f;
    }

    f32x4 acc0 = {0.f, 0.f, 0.f, 0.f}, acc1 = {0.f, 0.f, 0.f, 0.f};
    const int n0 = pw * 32;
    const unsigned short* wB0 = WhT + (size_t)b * FOUT * N_ + (size_t)(n0 + l16) * N_;
    const unsigned short* wB1 = wB0 + (size_t)16 * N_;

    for (int step = 0; step <= NCH; ++step) {
        if (producer) {
            if (step < NCH) {
                kb_phaseA(step, lane, pw, i0, adjB, f2b4, f1r, s_run,
                          &p[step & 1][0]);
            } else {
                // all chunks produced: publish row sums (full 64-lane reduce)
#pragma unroll
                for (int rr = 0; rr < 4; ++rr) {
                    float s = s_run[rr];
#pragma unroll
                    for (int o = 32; o; o >>= 1) s += __shfl_xor(s, o);
                    if (lane == 0) rs[pw * 4 + rr] = s;
                }
            }
        } else if (step >= 1) {
            const int c = step - 1;
            const unsigned short* pA = &p[c & 1][l16 * PR];
            const int kbase = c * CH;
#pragma unroll
            for (int ks = 0; ks < CH / 32; ++ks) {
                const int kof = ks * 32 + quad * 8;
                bf16x8 afr = *(const bf16x8*)&pA[kof];
                bf16x8 b0  = *(const bf16x8*)&wB0[kbase + kof];
                bf16x8 b1  = *(const bf16x8*)&wB1[kbase + kof];
                acc0 = __builtin_amdgcn_mfma_f32_16x16x32_bf16(afr, b0, acc0, 0, 0, 0);
                acc1 = __builtin_amdgcn_mfma_f32_16x16x32_bf16(afr, b1, acc1, 0, 0, 0);
            }
        }
        __syncthreads();   // single barrier site, reached by ALL threads
    }

    // ---- Epilogue (consumers): /rowsum, ELU, store ----
    if (!producer) {
#pragma unroll
        for (int r = 0; r < 4; ++r) {
            const int m = quad * 4 + r;
            const float inv = 1.f / rs[m];
            float v0 = acc0[r] * inv;
            float v1 = acc1[r] * inv;
            v0 = (v0 > 0.f) ? v0 : expm1f(v0);
            v1 = (v1 > 0.f) ? v1 : expm1f(v1);
            const size_t base = ((size_t)b * N_ + i0 + m) * FOUT + n0;
            out[base + l16]      = v0;
            out[base + 16 + l16] = v1;
        }
    }
}

// ---------------------------------------------------------------------------
extern "C" void kernel_launch(void* const* d_in, const int* in_sizes, int n_in,
                              void* d_out, int out_size, void* d_ws, size_t ws_size,
                              hipStream_t stream) {
    const float* x   = (const float*)d_in[0];
    const int*   adj = (const int*)d_in[1];
    const float* W   = (const float*)d_in[2];
    const float* a   = (const float*)d_in[3];
    float* out = (float*)d_out;

    // ws: WhT bf16 (4 MB) | Wt bf16 (64 KB) | f1 (64 KB) | f2 (64 KB)
    unsigned short* WhT = (unsigned short*)d_ws;
    unsigned short* Wt  = WhT + (size_t)B_ * FOUT * N_;
    float* f1 = (float*)(Wt + (size_t)FOUT * FIN);
    float* f2 = f1 + (size_t)B_ * N_;

    hipLaunchKernelGGL(k0_wt, dim3(FOUT), dim3(FIN), 0, stream, W, Wt);
    hipLaunchKernelGGL(ka_wh, dim3(B_ * N_ / 32), dim3(256), 0, stream,
                       x, Wt, a, WhT, f1, f2);
    hipLaunchKernelGGL(kb_attn, dim3(B_ * N_ / 16), dim3(512), 0, stream,
                       adj, WhT, f1, f2, out);
}